// Round 1
// baseline (702.816 us; speedup 1.0000x reference)
//
#include <hip/hip_runtime.h>
#include <hip/hip_bf16.h>

// ---------------------------------------------------------------------------
// Tiled row-blocked GEMM. RPBT=64 -> 782 blocks (~3/CU) instead of 196 (<=1/CU):
// the old RPB=256 left 60 CUs idle and 1 wave/SIMD elsewhere (no latency hiding).
// ---------------------------------------------------------------------------
template<int COLS, int K, int RPBT>
__global__ __launch_bounds__(256) void gemm_k(
    const float* __restrict__ X, const float* __restrict__ W,
    const float* __restrict__ bias, float* __restrict__ out,
    int nrows, float scale, int relu_in)
{
    constexpr int CPT = COLS / 8;
    constexpr int KT  = 32;
    constexpr int NKT = K / KT;
    constexpr int RT  = RPBT / 32;   // acc rows per thread

    __shared__ float sx[RPBT * 36];
    __shared__ float sWT[COLS * 33];

    const int tid = threadIdx.x;
    const int cg  = tid & 7;
    const int rg  = tid >> 3;
    const int r0  = blockIdx.x * RPBT;

    float acc[RT][CPT];
    #pragma unroll
    for (int r = 0; r < RT; ++r)
        #pragma unroll
        for (int c = 0; c < CPT; ++c) acc[r][c] = 0.f;

    for (int kt = 0; kt < NKT; ++kt) {
        #pragma unroll
        for (int j = 0; j < RT; ++j) {         // RPBT*8 float4s / 256 threads
            int i  = tid + j * 256;
            int r  = i >> 3;
            int k4 = i & 7;
            int gr = r0 + r; if (gr >= nrows) gr = nrows - 1;
            float4 v = *(const float4*)&X[(size_t)gr * K + kt * KT + k4 * 4];
            if (relu_in) {
                v.x = fmaxf(v.x, 0.f); v.y = fmaxf(v.y, 0.f);
                v.z = fmaxf(v.z, 0.f); v.w = fmaxf(v.w, 0.f);
            }
            if (scale != 1.f) { v.x *= scale; v.y *= scale; v.z *= scale; v.w *= scale; }
            *(float4*)&sx[r * 36 + k4 * 4] = v;
        }
        for (int i = tid; i < COLS * KT; i += 256) {
            int kl = i / COLS, c = i % COLS;
            sWT[c * 33 + kl] = W[(size_t)(kt * KT + kl) * COLS + c];
        }
        __syncthreads();

        #pragma unroll
        for (int k4 = 0; k4 < 8; ++k4) {
            float4 a[RT];
            #pragma unroll
            for (int r = 0; r < RT; ++r)
                a[r] = *(const float4*)&sx[(r * 32 + rg) * 36 + k4 * 4];
            #pragma unroll
            for (int cc = 0; cc < CPT; ++cc) {
                int c = cg * CPT + cc;
                float w0 = sWT[c * 33 + k4 * 4 + 0];
                float w1 = sWT[c * 33 + k4 * 4 + 1];
                float w2 = sWT[c * 33 + k4 * 4 + 2];
                float w3 = sWT[c * 33 + k4 * 4 + 3];
                #pragma unroll
                for (int r = 0; r < RT; ++r)
                    acc[r][cc] += a[r].x * w0 + a[r].y * w1 + a[r].z * w2 + a[r].w * w3;
            }
        }
        __syncthreads();
    }

    #pragma unroll
    for (int r = 0; r < RT; ++r) {
        int row = r0 + r * 32 + rg;
        if (row < nrows) {
            #pragma unroll
            for (int cc4 = 0; cc4 < CPT / 4; ++cc4) {
                int c = cg * CPT + cc4 * 4;
                float4 o;
                o.x = acc[r][cc4 * 4 + 0] + (bias ? bias[c + 0] : 0.f);
                o.y = acc[r][cc4 * 4 + 1] + (bias ? bias[c + 1] : 0.f);
                o.z = acc[r][cc4 * 4 + 2] + (bias ? bias[c + 2] : 0.f);
                o.w = acc[r][cc4 * 4 + 3] + (bias ? bias[c + 3] : 0.f);
                *(float4*)&out[(size_t)row * COLS + c] = o;
            }
        }
    }
}

// ---------------------------------------------------------------------------
// T-GEMM (proven): par[kq][n][32] = T[n, kq*256:+256] @ eh[kslice, 32]
// ---------------------------------------------------------------------------
__global__ __launch_bounds__(256, 4) void tgemm2_k(
    const float* __restrict__ T, const float* __restrict__ eh,
    float* __restrict__ par, int nrows)
{
    __shared__ float seh[256 * 32];   // 32 KB
    const int tid = threadIdx.x;
    const int ks  = blockIdx.y * 256;

    #pragma unroll
    for (int j = 0; j < 8; ++j) {
        int i = tid + j * 256;
        *(float4*)&seh[i * 4] = *(const float4*)&eh[(size_t)ks * 32 + (size_t)i * 4];
    }
    __syncthreads();

    int row = blockIdx.x * 256 + tid;
    int r   = row < nrows ? row : nrows - 1;
    const float* Tp = T + (size_t)r * 1024 + ks;

    float acc[32];
    #pragma unroll
    for (int c = 0; c < 32; ++c) acc[c] = 0.f;

    float4 t[8];
    #pragma unroll
    for (int q = 0; q < 8; ++q) t[q] = *(const float4*)&Tp[q * 4];

    for (int kc = 0; kc < 8; ++kc) {
        float4 tn[8];
        if (kc < 7) {
            #pragma unroll
            for (int q = 0; q < 8; ++q)
                tn[q] = *(const float4*)&Tp[(kc + 1) * 32 + q * 4];
        }
        #pragma unroll
        for (int q = 0; q < 8; ++q) {
            #pragma unroll
            for (int j = 0; j < 4; ++j) {
                float a = (j == 0) ? t[q].x : (j == 1) ? t[q].y : (j == 2) ? t[q].z : t[q].w;
                int k = kc * 32 + q * 4 + j;
                #pragma unroll
                for (int c4 = 0; c4 < 8; ++c4) {
                    float4 w = *(const float4*)&seh[k * 32 + c4 * 4];
                    acc[c4 * 4 + 0] += a * w.x;
                    acc[c4 * 4 + 1] += a * w.y;
                    acc[c4 * 4 + 2] += a * w.z;
                    acc[c4 * 4 + 3] += a * w.w;
                }
            }
        }
        #pragma unroll
        for (int q = 0; q < 8; ++q) t[q] = tn[q];
    }

    if (row < nrows) {
        float* p = par + (size_t)blockIdx.y * nrows * 32 + (size_t)row * 32;
        #pragma unroll
        for (int c4 = 0; c4 < 8; ++c4)
            *(float4*)&p[c4 * 4] = make_float4(acc[c4 * 4 + 0], acc[c4 * 4 + 1],
                                               acc[c4 * 4 + 2], acc[c4 * 4 + 3]);
    }
}

// ---------------------------------------------------------------------------
// Epilogue: shared = relu(sum_kq par + nfw + bg); classifier; softmax.
// ---------------------------------------------------------------------------
__global__ __launch_bounds__(256) void classify_k(
    const float* __restrict__ par, const float* __restrict__ nfw,
    const float* __restrict__ bg, const float* __restrict__ Wc1,
    const float* __restrict__ bc1, const float* __restrict__ Wc2,
    const float* __restrict__ bc2, float* __restrict__ out, int nrows)
{
    __shared__ float sWc1T[1024];
    __shared__ float sWc2[64];
    __shared__ float sb[66];

    int tid = threadIdx.x;
    for (int i = tid; i < 1024; i += 256)
        sWc1T[(i & 31) * 32 + (i >> 5)] = Wc1[i];
    if (tid < 64) sWc2[tid] = Wc2[tid];
    if (tid < 32)      sb[tid] = bc1[tid];
    else if (tid < 64) sb[tid] = bg[tid - 32];
    else if (tid < 66) sb[tid] = bc2[tid - 64];
    __syncthreads();

    int row = blockIdx.x * 256 + tid;
    if (row >= nrows) return;

    size_t stride = (size_t)nrows * 32;
    float4 sh4[8];
    #pragma unroll
    for (int i4 = 0; i4 < 8; ++i4) {
        const float* base = par + (size_t)row * 32 + i4 * 4;
        float4 v0 = *(const float4*)(base);
        float4 v1 = *(const float4*)(base + stride);
        float4 v2 = *(const float4*)(base + 2 * stride);
        float4 v3 = *(const float4*)(base + 3 * stride);
        float4 nf = *(const float4*)&nfw[(size_t)row * 32 + i4 * 4];
        float4 o;
        o.x = fmaxf(v0.x + v1.x + v2.x + v3.x + nf.x + sb[32 + i4 * 4 + 0], 0.f);
        o.y = fmaxf(v0.y + v1.y + v2.y + v3.y + nf.y + sb[32 + i4 * 4 + 1], 0.f);
        o.z = fmaxf(v0.z + v1.z + v2.z + v3.z + nf.z + sb[32 + i4 * 4 + 2], 0.f);
        o.w = fmaxf(v0.w + v1.w + v2.w + v3.w + nf.w + sb[32 + i4 * 4 + 3], 0.f);
        sh4[i4] = o;
    }

    float l0 = sb[64], l1 = sb[65];
    #pragma unroll
    for (int jj = 0; jj < 32; ++jj) {
        float s = sb[jj];
        #pragma unroll
        for (int i4 = 0; i4 < 8; ++i4) {
            float4 w4 = *(const float4*)&sWc1T[jj * 32 + i4 * 4];
            s += sh4[i4].x * w4.x + sh4[i4].y * w4.y
               + sh4[i4].z * w4.z + sh4[i4].w * w4.w;
        }
        s = fmaxf(s, 0.f);
        l0 += s * sWc2[jj * 2 + 0];
        l1 += s * sWc2[jj * 2 + 1];
    }
    float p0 = 1.f / (1.f + expf(l1 - l0));
    float p1 = 1.f / (1.f + expf(l0 - l1));
    *(float2*)&out[(size_t)row * 2] = make_float2(p0, p1);
}

// --------------------------- CSR construction ------------------------------
__global__ void hist_k(const int* __restrict__ dst, int* __restrict__ deg, int E)
{
    int e = blockIdx.x * 256 + threadIdx.x;
    if (e < E) atomicAdd(&deg[dst[e]], 1);
}

__global__ void scan1_k(const int* __restrict__ deg, int* __restrict__ bsum, int N)
{
    __shared__ int s[256];
    int t = threadIdx.x, i = blockIdx.x * 256 + t;
    s[t] = (i < N) ? deg[i] : 0;
    __syncthreads();
    for (int off = 128; off > 0; off >>= 1) {
        if (t < off) s[t] += s[t + off];
        __syncthreads();
    }
    if (t == 0) bsum[blockIdx.x] = s[0];
}

__global__ void scan2_k(const int* __restrict__ bsum, int* __restrict__ boff,
                        int NB, int* __restrict__ rsN)
{
    __shared__ int s[256];
    int t = threadIdx.x;
    int v = (t < NB) ? bsum[t] : 0;
    s[t] = v;
    __syncthreads();
    for (int off = 1; off < 256; off <<= 1) {
        int u = (t >= off) ? s[t - off] : 0;
        __syncthreads();
        s[t] += u;
        __syncthreads();
    }
    if (t < NB) boff[t] = s[t] - v;
    if (t == NB - 1) *rsN = s[t];
}

__global__ void scan3_k(const int* __restrict__ deg, const int* __restrict__ boff,
                        int* __restrict__ rs, int* __restrict__ cur, int N)
{
    __shared__ int s[256];
    int t = threadIdx.x, i = blockIdx.x * 256 + t;
    int v = (i < N) ? deg[i] : 0;
    s[t] = v;
    __syncthreads();
    for (int off = 1; off < 256; off <<= 1) {
        int u = (t >= off) ? s[t - off] : 0;
        __syncthreads();
        s[t] += u;
        __syncthreads();
    }
    if (i < N) {
        int ex = boff[blockIdx.x] + s[t] - v;
        rs[i] = ex;
        cur[i] = ex;
    }
}

// packed (src, weight-bits) per CSR slot
__global__ void fill_k(const int* __restrict__ src, const int* __restrict__ dst,
                       const float* __restrict__ ew, int* __restrict__ cur,
                       int2* __restrict__ epk, int E)
{
    int e = blockIdx.x * 256 + threadIdx.x;
    if (e < E) {
        int pos = atomicAdd(&cur[dst[e]], 1);
        epk[pos] = make_int2(src[e], __float_as_int(ew[e]));
    }
}

// --------------------------- CSR gathers -----------------------------------
// Wave-per-node: lanes = (edge-slot e4 in 0..3, chunk ch in 0..15).
// 4 edges in flight, epk reads are one 32B contiguous transaction/iter,
// runtime per wave = ceil(deg/4) -> near-perfect balance across 50k waves
// (old thread-per-(node,chunk) paid E[max deg over 4 nodes] ~ 1.35x mean).
// Tree-reduce the 4 partials with 2 shfl_xor steps; lane group 0 writes.
__global__ __launch_bounds__(256) void gather64w_k(
    const float* __restrict__ hp, const int2* __restrict__ epk,
    const int* __restrict__ rs, float* __restrict__ outv, int N)
{
    int wid  = (blockIdx.x * 256 + threadIdx.x) >> 6;   // wave id == node
    if (wid >= N) return;
    int lane = threadIdx.x & 63;
    int e4   = lane >> 4;        // which of 4 concurrent edges
    int ch   = lane & 15;        // float4 chunk of the 64-d row
    int j0 = rs[wid], j1 = rs[wid + 1];

    float4 acc = make_float4(0.f, 0.f, 0.f, 0.f);
    for (int j = j0 + e4; j < j1; j += 4) {
        int2 e = epk[j];
        float w = __int_as_float(e.y);
        float4 v = *(const float4*)&hp[(size_t)e.x * 64 + ch * 4];
        acc.x += v.x * w; acc.y += v.y * w;
        acc.z += v.z * w; acc.w += v.w * w;
    }
    #pragma unroll
    for (int off = 16; off < 64; off <<= 1) {
        acc.x += __shfl_xor(acc.x, off);
        acc.y += __shfl_xor(acc.y, off);
        acc.z += __shfl_xor(acc.z, off);
        acc.w += __shfl_xor(acc.w, off);
    }
    if (e4 == 0)
        *(float4*)&outv[(size_t)wid * 64 + ch * 4] = acc;
}

// 32-d variant: lanes = (edge-slot e8 in 0..7, chunk ch in 0..7); 8 edges in
// flight; 3 shfl_xor steps; lanes 0..7 write the 128B row.
template<bool WEIGHTED, bool RELU>
__global__ __launch_bounds__(256) void gather32w_k(
    const float* __restrict__ hp, const int2* __restrict__ epk,
    const int* __restrict__ rs, float* __restrict__ outv, int N)
{
    int wid  = (blockIdx.x * 256 + threadIdx.x) >> 6;   // wave id == node
    if (wid >= N) return;
    int lane = threadIdx.x & 63;
    int e8   = lane >> 3;
    int ch   = lane & 7;
    int j0 = rs[wid], j1 = rs[wid + 1];

    float4 acc = make_float4(0.f, 0.f, 0.f, 0.f);
    for (int j = j0 + e8; j < j1; j += 8) {
        int2 e = epk[j];
        float w = WEIGHTED ? __int_as_float(e.y) : 1.f;
        float4 v = *(const float4*)&hp[(size_t)e.x * 32 + ch * 4];
        if (RELU) {
            v.x = fmaxf(v.x, 0.f); v.y = fmaxf(v.y, 0.f);
            v.z = fmaxf(v.z, 0.f); v.w = fmaxf(v.w, 0.f);
        }
        acc.x += v.x * w; acc.y += v.y * w;
        acc.z += v.z * w; acc.w += v.w * w;
    }
    #pragma unroll
    for (int off = 8; off < 64; off <<= 1) {
        acc.x += __shfl_xor(acc.x, off);
        acc.y += __shfl_xor(acc.y, off);
        acc.z += __shfl_xor(acc.z, off);
        acc.w += __shfl_xor(acc.w, off);
    }
    if (e8 == 0)
        *(float4*)&outv[(size_t)wid * 32 + ch * 4] = acc;
}

// ----------------------- small edge-side matmuls ---------------------------
__global__ void efwe_k(const float* __restrict__ ef, const float* __restrict__ We,
                       float* __restrict__ tmp)
{
    int idx = blockIdx.x * 256 + threadIdx.x;
    int row = idx >> 5, c = idx & 31;
    float s = 0.f;
    #pragma unroll
    for (int k = 0; k < 64; ++k)
        s += ef[row * 64 + k] * We[k * 32 + c];
    tmp[row * 32 + c] = s;
}

__global__ void adjmm_k(const float* __restrict__ adj, const float* __restrict__ tmp,
                        float* __restrict__ edge_h)
{
    int kq     = blockIdx.x & 3;
    int rowblk = blockIdx.x >> 2;
    int r = rowblk * 8 + (threadIdx.x >> 5);
    int c = threadIdx.x & 31;
    float s = 0.f;
    int k0 = kq * 256;
    #pragma unroll 8
    for (int k = k0; k < k0 + 256; ++k)
        s += adj[r * 1024 + k] * tmp[k * 32 + c];
    atomicAdd(&edge_h[r * 32 + c], s);
}

// ---------------------------------------------------------------------------
extern "C" void kernel_launch(void* const* d_in, const int* in_sizes, int n_in,
                              void* d_out, int out_size, void* d_ws, size_t ws_size,
                              hipStream_t stream)
{
    const float* x   = (const float*)d_in[0];
    const int*   ei  = (const int*)  d_in[1];
    const float* ew  = (const float*)d_in[2];
    const float* ef  = (const float*)d_in[3];
    const float* adj = (const float*)d_in[4];
    const float* T   = (const float*)d_in[5];
    const float* W1  = (const float*)d_in[6];
    const float* b1  = (const float*)d_in[7];
    const float* W2  = (const float*)d_in[8];
    const float* b2  = (const float*)d_in[9];
    const float* Wn  = (const float*)d_in[10];
    const float* We  = (const float*)d_in[11];
    const float* bg  = (const float*)d_in[12];
    const float* Wc1 = (const float*)d_in[13];
    const float* bc1 = (const float*)d_in[14];
    const float* Wc2 = (const float*)d_in[15];
    const float* bc2 = (const float*)d_in[16];
    float* out = (float*)d_out;

    const int N = in_sizes[0] / 128;   // 50000
    const int E = in_sizes[1] / 2;     // 1000000
    const int* srcIdx = ei;
    const int* dstIdx = ei + E;

    // ---- workspace layout (floats) — identical footprint to proven R3 ----
    float* ws = (float*)d_ws;
    size_t o = 0;
    float* h1acc  = ws + o; o += (size_t)N * 64;
    float* h2acc  = ws + o; o += (size_t)N * 32;
    float* nfacc  = ws + o; o += (size_t)N * 32;
    float* edge_h = ws + o; o += 1024 * 32;
    float* tmp    = ws + o; o += 1024 * 32;
    float* nfw    = ws + o; o += (size_t)N * 32;
    float* par    = ws + o; o += (size_t)N * 128;  // aliases h1p/h2p
    float* h1p    = par;                           // dead before tgemm writes
    float* h2p    = par + (size_t)N * 64;          // dead before tgemm writes
    int2*  epk    = (int2*)(ws + o);  o += (size_t)E * 2;
    int*   deg    = (int*)(ws + o);   o += N;
    int*   rs     = (int*)(ws + o);   o += N + 1;
    int*   cur    = (int*)(ws + o);   o += N + 1;
    int*   bsum   = (int*)(ws + o);   o += 256;
    int*   boff   = (int*)(ws + o);   o += 256;

    const int NB  = (N + 255) / 256;   // 196 (scans / tgemm / classify)
    const int NBG = (N + 63) / 64;     // 782 (gemm blocks, ~3/CU)
    const int NBW = (N * 64 + 255) / 256;   // wave-per-node gathers: 12500

    (void)hipMemsetAsync(deg, 0, (size_t)N * sizeof(int), stream);
    (void)hipMemsetAsync(edge_h, 0, 1024 * 32 * sizeof(float), stream);

    // 1. h1p = x @ W1 + b1
    gemm_k<64, 128, 64><<<NBG, 256, 0, stream>>>(x, W1, b1, h1p, N, 1.f, 0);

    // 2. CSR build
    hist_k<<<(E + 255) / 256, 256, 0, stream>>>(dstIdx, deg, E);
    scan1_k<<<NB, 256, 0, stream>>>(deg, bsum, N);
    scan2_k<<<1, 256, 0, stream>>>(bsum, boff, NB, rs + N);
    scan3_k<<<NB, 256, 0, stream>>>(deg, boff, rs, cur, N);
    fill_k<<<(E + 255) / 256, 256, 0, stream>>>(srcIdx, dstIdx, ew, cur, epk, E);

    // 3. h1acc[n] = sum_{e: dst=n} w_e * h1p[src_e]
    gather64w_k<<<NBW, 256, 0, stream>>>(h1p, epk, rs, h1acc, N);

    // 4. h2p = relu(h1acc) @ W2 + b2
    gemm_k<32, 64, 64><<<NBG, 256, 0, stream>>>(h1acc, W2, b2, h2p, N, 1.f, 1);

    // 5. h2acc[n] = sum w_e * h2p[src_e]
    gather32w_k<true, false><<<NBW, 256, 0, stream>>>(h2p, epk, rs, h2acc, N);

    // 6. nfacc[n] = sum relu(h2acc)[src_e]
    gather32w_k<false, true><<<NBW, 256, 0, stream>>>(h2acc, epk, rs, nfacc, N);

    // 7. edge_h = adj_e @ (ef @ We)
    efwe_k<<<128, 256, 0, stream>>>(ef, We, tmp);
    adjmm_k<<<512, 256, 0, stream>>>(adj, tmp, edge_h);

    // 8. nfw = (nfacc / E) @ Wn
    gemm_k<32, 32, 64><<<NBG, 256, 0, stream>>>(nfacc, Wn, nullptr, nfw, N, 1.f / (float)E, 0);

    // 9. par[kq] = T[:, kq*256:+256] @ edge_h[kslice]
    tgemm2_k<<<dim3(NB, 4), 256, 0, stream>>>(T, edge_h, par, N);

    // 10. out = softmax(classifier(relu(sum par + nfw + bg)))
    classify_k<<<NB, 256, 0, stream>>>(par, nfw, bg, Wc1, bc1, Wc2, bc2, out, N);
}

// Round 2
// 687.521 us; speedup vs baseline: 1.0222x; 1.0222x over previous
//
#include <hip/hip_runtime.h>
#include <hip/hip_fp16.h>

// ---------------------------------------------------------------------------
// Tiled row-blocked GEMM. RPBT=64 -> 782 blocks (~3/CU). OUTH=1 stores the
// output as fp16 (gather tables): halves the random-read bytes downstream.
// ---------------------------------------------------------------------------
template<int COLS, int K, int RPBT, int OUTH>
__global__ __launch_bounds__(256) void gemm_k(
    const float* __restrict__ X, const float* __restrict__ W,
    const float* __restrict__ bias, void* __restrict__ outp,
    int nrows, float scale, int relu_in)
{
    constexpr int CPT = COLS / 8;
    constexpr int KT  = 32;
    constexpr int NKT = K / KT;
    constexpr int RT  = RPBT / 32;   // acc rows per thread

    __shared__ float sx[RPBT * 36];
    __shared__ float sWT[COLS * 33];

    const int tid = threadIdx.x;
    const int cg  = tid & 7;
    const int rg  = tid >> 3;
    const int r0  = blockIdx.x * RPBT;

    float acc[RT][CPT];
    #pragma unroll
    for (int r = 0; r < RT; ++r)
        #pragma unroll
        for (int c = 0; c < CPT; ++c) acc[r][c] = 0.f;

    for (int kt = 0; kt < NKT; ++kt) {
        #pragma unroll
        for (int j = 0; j < RT; ++j) {
            int i  = tid + j * 256;
            int r  = i >> 3;
            int k4 = i & 7;
            int gr = r0 + r; if (gr >= nrows) gr = nrows - 1;
            float4 v = *(const float4*)&X[(size_t)gr * K + kt * KT + k4 * 4];
            if (relu_in) {
                v.x = fmaxf(v.x, 0.f); v.y = fmaxf(v.y, 0.f);
                v.z = fmaxf(v.z, 0.f); v.w = fmaxf(v.w, 0.f);
            }
            if (scale != 1.f) { v.x *= scale; v.y *= scale; v.z *= scale; v.w *= scale; }
            *(float4*)&sx[r * 36 + k4 * 4] = v;
        }
        for (int i = tid; i < COLS * KT; i += 256) {
            int kl = i / COLS, c = i % COLS;
            sWT[c * 33 + kl] = W[(size_t)(kt * KT + kl) * COLS + c];
        }
        __syncthreads();

        #pragma unroll
        for (int k4 = 0; k4 < 8; ++k4) {
            float4 a[RT];
            #pragma unroll
            for (int r = 0; r < RT; ++r)
                a[r] = *(const float4*)&sx[(r * 32 + rg) * 36 + k4 * 4];
            #pragma unroll
            for (int cc = 0; cc < CPT; ++cc) {
                int c = cg * CPT + cc;
                float w0 = sWT[c * 33 + k4 * 4 + 0];
                float w1 = sWT[c * 33 + k4 * 4 + 1];
                float w2 = sWT[c * 33 + k4 * 4 + 2];
                float w3 = sWT[c * 33 + k4 * 4 + 3];
                #pragma unroll
                for (int r = 0; r < RT; ++r)
                    acc[r][cc] += a[r].x * w0 + a[r].y * w1 + a[r].z * w2 + a[r].w * w3;
            }
        }
        __syncthreads();
    }

    #pragma unroll
    for (int r = 0; r < RT; ++r) {
        int row = r0 + r * 32 + rg;
        if (row < nrows) {
            #pragma unroll
            for (int cc4 = 0; cc4 < CPT / 4; ++cc4) {
                int c = cg * CPT + cc4 * 4;
                float4 o;
                o.x = acc[r][cc4 * 4 + 0] + (bias ? bias[c + 0] : 0.f);
                o.y = acc[r][cc4 * 4 + 1] + (bias ? bias[c + 1] : 0.f);
                o.z = acc[r][cc4 * 4 + 2] + (bias ? bias[c + 2] : 0.f);
                o.w = acc[r][cc4 * 4 + 3] + (bias ? bias[c + 3] : 0.f);
                if constexpr (OUTH) {
                    __half2 h0 = __floats2half2_rn(o.x, o.y);
                    __half2 h1 = __floats2half2_rn(o.z, o.w);
                    uint2 u;
                    u.x = *(unsigned int*)&h0;
                    u.y = *(unsigned int*)&h1;
                    *(uint2*)&((__half*)outp)[(size_t)row * COLS + c] = u;
                } else {
                    *(float4*)&((float*)outp)[(size_t)row * COLS + c] = o;
                }
            }
        }
    }
}

// ---------------------------------------------------------------------------
// T-GEMM (proven): par[kq][n][32] = T[n, kq*256:+256] @ eh[kslice, 32]
// ---------------------------------------------------------------------------
__global__ __launch_bounds__(256, 4) void tgemm2_k(
    const float* __restrict__ T, const float* __restrict__ eh,
    float* __restrict__ par, int nrows)
{
    __shared__ float seh[256 * 32];   // 32 KB
    const int tid = threadIdx.x;
    const int ks  = blockIdx.y * 256;

    #pragma unroll
    for (int j = 0; j < 8; ++j) {
        int i = tid + j * 256;
        *(float4*)&seh[i * 4] = *(const float4*)&eh[(size_t)ks * 32 + (size_t)i * 4];
    }
    __syncthreads();

    int row = blockIdx.x * 256 + tid;
    int r   = row < nrows ? row : nrows - 1;
    const float* Tp = T + (size_t)r * 1024 + ks;

    float acc[32];
    #pragma unroll
    for (int c = 0; c < 32; ++c) acc[c] = 0.f;

    float4 t[8];
    #pragma unroll
    for (int q = 0; q < 8; ++q) t[q] = *(const float4*)&Tp[q * 4];

    for (int kc = 0; kc < 8; ++kc) {
        float4 tn[8];
        if (kc < 7) {
            #pragma unroll
            for (int q = 0; q < 8; ++q)
                tn[q] = *(const float4*)&Tp[(kc + 1) * 32 + q * 4];
        }
        #pragma unroll
        for (int q = 0; q < 8; ++q) {
            #pragma unroll
            for (int j = 0; j < 4; ++j) {
                float a = (j == 0) ? t[q].x : (j == 1) ? t[q].y : (j == 2) ? t[q].z : t[q].w;
                int k = kc * 32 + q * 4 + j;
                #pragma unroll
                for (int c4 = 0; c4 < 8; ++c4) {
                    float4 w = *(const float4*)&seh[k * 32 + c4 * 4];
                    acc[c4 * 4 + 0] += a * w.x;
                    acc[c4 * 4 + 1] += a * w.y;
                    acc[c4 * 4 + 2] += a * w.z;
                    acc[c4 * 4 + 3] += a * w.w;
                }
            }
        }
        #pragma unroll
        for (int q = 0; q < 8; ++q) t[q] = tn[q];
    }

    if (row < nrows) {
        float* p = par + (size_t)blockIdx.y * nrows * 32 + (size_t)row * 32;
        #pragma unroll
        for (int c4 = 0; c4 < 8; ++c4)
            *(float4*)&p[c4 * 4] = make_float4(acc[c4 * 4 + 0], acc[c4 * 4 + 1],
                                               acc[c4 * 4 + 2], acc[c4 * 4 + 3]);
    }
}

// ---------------------------------------------------------------------------
// Fused epilogue: nfw = (nfacc/E)@Wn in-thread, shared = relu(sum_kq par +
// nfw + bg), classifier, softmax.  (removes the step-8 GEMM dispatch + 12.8MB
// of nfw round-trip)
// ---------------------------------------------------------------------------
__global__ __launch_bounds__(256) void classify2_k(
    const float* __restrict__ par, const float* __restrict__ nfacc,
    const float* __restrict__ Wn, const float* __restrict__ bg,
    const float* __restrict__ Wc1, const float* __restrict__ bc1,
    const float* __restrict__ Wc2, const float* __restrict__ bc2,
    float* __restrict__ out, int nrows, float invE)
{
    __shared__ float sWn[1024];     // Wn[k][c] row-major, broadcast reads
    __shared__ float sWc1T[1024];
    __shared__ float sWc2[64];
    __shared__ float sb[66];

    int tid = threadIdx.x;
    for (int i = tid; i < 1024; i += 256) {
        sWn[i] = Wn[i];
        sWc1T[(i & 31) * 32 + (i >> 5)] = Wc1[i];
    }
    if (tid < 64) sWc2[tid] = Wc2[tid];
    if (tid < 32)      sb[tid] = bc1[tid];
    else if (tid < 64) sb[tid] = bg[tid - 32];
    else if (tid < 66) sb[tid] = bc2[tid - 64];
    __syncthreads();

    int row = blockIdx.x * 256 + tid;
    if (row >= nrows) return;

    // nf = nfacc_row / E
    float nf[32];
    #pragma unroll
    for (int i4 = 0; i4 < 8; ++i4) {
        float4 v = *(const float4*)&nfacc[(size_t)row * 32 + i4 * 4];
        nf[i4 * 4 + 0] = v.x * invE; nf[i4 * 4 + 1] = v.y * invE;
        nf[i4 * 4 + 2] = v.z * invE; nf[i4 * 4 + 3] = v.w * invE;
    }

    // acc = bg + nf @ Wn
    float acc[32];
    #pragma unroll
    for (int c = 0; c < 32; ++c) acc[c] = sb[32 + c];
    #pragma unroll
    for (int k = 0; k < 32; ++k) {
        float a = nf[k];
        #pragma unroll
        for (int c4 = 0; c4 < 8; ++c4) {
            float4 w = *(const float4*)&sWn[k * 32 + c4 * 4];
            acc[c4 * 4 + 0] += a * w.x;
            acc[c4 * 4 + 1] += a * w.y;
            acc[c4 * 4 + 2] += a * w.z;
            acc[c4 * 4 + 3] += a * w.w;
        }
    }

    // acc += sum_kq par;  relu
    size_t stride = (size_t)nrows * 32;
    #pragma unroll
    for (int i4 = 0; i4 < 8; ++i4) {
        const float* base = par + (size_t)row * 32 + i4 * 4;
        float4 v0 = *(const float4*)(base);
        float4 v1 = *(const float4*)(base + stride);
        float4 v2 = *(const float4*)(base + 2 * stride);
        float4 v3 = *(const float4*)(base + 3 * stride);
        acc[i4 * 4 + 0] = fmaxf(acc[i4 * 4 + 0] + v0.x + v1.x + v2.x + v3.x, 0.f);
        acc[i4 * 4 + 1] = fmaxf(acc[i4 * 4 + 1] + v0.y + v1.y + v2.y + v3.y, 0.f);
        acc[i4 * 4 + 2] = fmaxf(acc[i4 * 4 + 2] + v0.z + v1.z + v2.z + v3.z, 0.f);
        acc[i4 * 4 + 3] = fmaxf(acc[i4 * 4 + 3] + v0.w + v1.w + v2.w + v3.w, 0.f);
    }

    float l0 = sb[64], l1 = sb[65];
    #pragma unroll
    for (int jj = 0; jj < 32; ++jj) {
        float s = sb[jj];
        #pragma unroll
        for (int k4 = 0; k4 < 8; ++k4) {
            float4 w4 = *(const float4*)&sWc1T[jj * 32 + k4 * 4];
            s += acc[k4 * 4 + 0] * w4.x + acc[k4 * 4 + 1] * w4.y
               + acc[k4 * 4 + 2] * w4.z + acc[k4 * 4 + 3] * w4.w;
        }
        s = fmaxf(s, 0.f);
        l0 += s * sWc2[jj * 2 + 0];
        l1 += s * sWc2[jj * 2 + 1];
    }
    float p0 = 1.f / (1.f + expf(l1 - l0));
    float p1 = 1.f / (1.f + expf(l0 - l1));
    *(float2*)&out[(size_t)row * 2] = make_float2(p0, p1);
}

// --------------------------- CSR construction ------------------------------
__global__ void hist_k(const int* __restrict__ dst, int* __restrict__ deg, int E)
{
    int e = blockIdx.x * 256 + threadIdx.x;
    if (e < E) atomicAdd(&deg[dst[e]], 1);
}

__global__ void scan1_k(const int* __restrict__ deg, int* __restrict__ bsum, int N)
{
    __shared__ int s[256];
    int t = threadIdx.x, i = blockIdx.x * 256 + t;
    s[t] = (i < N) ? deg[i] : 0;
    __syncthreads();
    for (int off = 128; off > 0; off >>= 1) {
        if (t < off) s[t] += s[t + off];
        __syncthreads();
    }
    if (t == 0) bsum[blockIdx.x] = s[0];
}

__global__ void scan2_k(const int* __restrict__ bsum, int* __restrict__ boff,
                        int NB, int* __restrict__ rsN)
{
    __shared__ int s[256];
    int t = threadIdx.x;
    int v = (t < NB) ? bsum[t] : 0;
    s[t] = v;
    __syncthreads();
    for (int off = 1; off < 256; off <<= 1) {
        int u = (t >= off) ? s[t - off] : 0;
        __syncthreads();
        s[t] += u;
        __syncthreads();
    }
    if (t < NB) boff[t] = s[t] - v;
    if (t == NB - 1) *rsN = s[t];
}

__global__ void scan3_k(const int* __restrict__ deg, const int* __restrict__ boff,
                        int* __restrict__ rs, int* __restrict__ cur, int N)
{
    __shared__ int s[256];
    int t = threadIdx.x, i = blockIdx.x * 256 + t;
    int v = (i < N) ? deg[i] : 0;
    s[t] = v;
    __syncthreads();
    for (int off = 1; off < 256; off <<= 1) {
        int u = (t >= off) ? s[t - off] : 0;
        __syncthreads();
        s[t] += u;
        __syncthreads();
    }
    if (i < N) {
        int ex = boff[blockIdx.x] + s[t] - v;
        rs[i] = ex;
        cur[i] = ex;
    }
}

// packed (src, weight-bits) per CSR slot
__global__ void fill_k(const int* __restrict__ src, const int* __restrict__ dst,
                       const float* __restrict__ ew, int* __restrict__ cur,
                       int2* __restrict__ epk, int E)
{
    int e = blockIdx.x * 256 + threadIdx.x;
    if (e < E) {
        int pos = atomicAdd(&cur[dst[e]], 1);
        epk[pos] = make_int2(src[e], __float_as_int(ew[e]));
    }
}

// --------------------------- CSR gathers (fp16 tables) ----------------------
// Wave-per-node; tables stored fp16 so the random row-read stream is halved
// (256B->128B for 64-d, 128B->64B for 32-d) and h2p/h2r (3.2MB) fit per-XCD L2.
// Accumulation in fp32.
__global__ __launch_bounds__(256) void gather64h_k(
    const __half* __restrict__ hp, const int2* __restrict__ epk,
    const int* __restrict__ rs, float* __restrict__ outv, int N)
{
    int wid  = (blockIdx.x * 256 + threadIdx.x) >> 6;   // wave id == node
    if (wid >= N) return;
    int lane = threadIdx.x & 63;
    int e4   = lane >> 4;        // which of 4 concurrent edges
    int ch   = lane & 15;        // 4-half chunk of the 64-d row
    int j0 = rs[wid], j1 = rs[wid + 1];

    float4 acc = make_float4(0.f, 0.f, 0.f, 0.f);
    for (int j = j0 + e4; j < j1; j += 4) {
        int2 e = epk[j];
        float w = __int_as_float(e.y);
        uint2 u = *(const uint2*)&hp[(size_t)e.x * 64 + ch * 4];
        float2 a = __half22float2(*(__half2*)&u.x);
        float2 b = __half22float2(*(__half2*)&u.y);
        acc.x += a.x * w; acc.y += a.y * w;
        acc.z += b.x * w; acc.w += b.y * w;
    }
    #pragma unroll
    for (int off = 16; off < 64; off <<= 1) {
        acc.x += __shfl_xor(acc.x, off);
        acc.y += __shfl_xor(acc.y, off);
        acc.z += __shfl_xor(acc.z, off);
        acc.w += __shfl_xor(acc.w, off);
    }
    if (e4 == 0)
        *(float4*)&outv[(size_t)wid * 64 + ch * 4] = acc;
}

// weighted 32-d fp16 gather; epilogue applies relu and stores fp16 (feeds the
// next unweighted gather directly).
__global__ __launch_bounds__(256) void gather32h_wr_k(
    const __half* __restrict__ hp, const int2* __restrict__ epk,
    const int* __restrict__ rs, __half* __restrict__ outh, int N)
{
    int wid  = (blockIdx.x * 256 + threadIdx.x) >> 6;
    if (wid >= N) return;
    int lane = threadIdx.x & 63;
    int e8   = lane >> 3;
    int ch   = lane & 7;
    int j0 = rs[wid], j1 = rs[wid + 1];

    float4 acc = make_float4(0.f, 0.f, 0.f, 0.f);
    for (int j = j0 + e8; j < j1; j += 8) {
        int2 e = epk[j];
        float w = __int_as_float(e.y);
        uint2 u = *(const uint2*)&hp[(size_t)e.x * 32 + ch * 4];
        float2 a = __half22float2(*(__half2*)&u.x);
        float2 b = __half22float2(*(__half2*)&u.y);
        acc.x += a.x * w; acc.y += a.y * w;
        acc.z += b.x * w; acc.w += b.y * w;
    }
    #pragma unroll
    for (int off = 8; off < 64; off <<= 1) {
        acc.x += __shfl_xor(acc.x, off);
        acc.y += __shfl_xor(acc.y, off);
        acc.z += __shfl_xor(acc.z, off);
        acc.w += __shfl_xor(acc.w, off);
    }
    if (e8 == 0) {
        __half2 h0 = __floats2half2_rn(fmaxf(acc.x, 0.f), fmaxf(acc.y, 0.f));
        __half2 h1 = __floats2half2_rn(fmaxf(acc.z, 0.f), fmaxf(acc.w, 0.f));
        uint2 u;
        u.x = *(unsigned int*)&h0;
        u.y = *(unsigned int*)&h1;
        *(uint2*)&outh[(size_t)wid * 32 + ch * 4] = u;
    }
}

// unweighted 32-d fp16 gather -> fp32 output (nfacc)
__global__ __launch_bounds__(256) void gather32h_uf_k(
    const __half* __restrict__ hp, const int2* __restrict__ epk,
    const int* __restrict__ rs, float* __restrict__ outv, int N)
{
    int wid  = (blockIdx.x * 256 + threadIdx.x) >> 6;
    if (wid >= N) return;
    int lane = threadIdx.x & 63;
    int e8   = lane >> 3;
    int ch   = lane & 7;
    int j0 = rs[wid], j1 = rs[wid + 1];

    float4 acc = make_float4(0.f, 0.f, 0.f, 0.f);
    for (int j = j0 + e8; j < j1; j += 8) {
        int2 e = epk[j];
        uint2 u = *(const uint2*)&hp[(size_t)e.x * 32 + ch * 4];
        float2 a = __half22float2(*(__half2*)&u.x);
        float2 b = __half22float2(*(__half2*)&u.y);
        acc.x += a.x; acc.y += a.y;
        acc.z += b.x; acc.w += b.y;
    }
    #pragma unroll
    for (int off = 8; off < 64; off <<= 1) {
        acc.x += __shfl_xor(acc.x, off);
        acc.y += __shfl_xor(acc.y, off);
        acc.z += __shfl_xor(acc.z, off);
        acc.w += __shfl_xor(acc.w, off);
    }
    if (e8 == 0)
        *(float4*)&outv[(size_t)wid * 32 + ch * 4] = acc;
}

// ----------------------- small edge-side matmuls ---------------------------
__global__ void efwe_k(const float* __restrict__ ef, const float* __restrict__ We,
                       float* __restrict__ tmp)
{
    int idx = blockIdx.x * 256 + threadIdx.x;
    int row = idx >> 5, c = idx & 31;
    float s = 0.f;
    #pragma unroll
    for (int k = 0; k < 64; ++k)
        s += ef[row * 64 + k] * We[k * 32 + c];
    tmp[row * 32 + c] = s;
}

__global__ void adjmm_k(const float* __restrict__ adj, const float* __restrict__ tmp,
                        float* __restrict__ edge_h)
{
    int kq     = blockIdx.x & 3;
    int rowblk = blockIdx.x >> 2;
    int r = rowblk * 8 + (threadIdx.x >> 5);
    int c = threadIdx.x & 31;
    float s = 0.f;
    int k0 = kq * 256;
    #pragma unroll 8
    for (int k = k0; k < k0 + 256; ++k)
        s += adj[r * 1024 + k] * tmp[k * 32 + c];
    atomicAdd(&edge_h[r * 32 + c], s);
}

// ---------------------------------------------------------------------------
extern "C" void kernel_launch(void* const* d_in, const int* in_sizes, int n_in,
                              void* d_out, int out_size, void* d_ws, size_t ws_size,
                              hipStream_t stream)
{
    const float* x   = (const float*)d_in[0];
    const int*   ei  = (const int*)  d_in[1];
    const float* ew  = (const float*)d_in[2];
    const float* ef  = (const float*)d_in[3];
    const float* adj = (const float*)d_in[4];
    const float* T   = (const float*)d_in[5];
    const float* W1  = (const float*)d_in[6];
    const float* b1  = (const float*)d_in[7];
    const float* W2  = (const float*)d_in[8];
    const float* b2  = (const float*)d_in[9];
    const float* Wn  = (const float*)d_in[10];
    const float* We  = (const float*)d_in[11];
    const float* bg  = (const float*)d_in[12];
    const float* Wc1 = (const float*)d_in[13];
    const float* bc1 = (const float*)d_in[14];
    const float* Wc2 = (const float*)d_in[15];
    const float* bc2 = (const float*)d_in[16];
    float* out = (float*)d_out;

    const int N = in_sizes[0] / 128;   // 50000
    const int E = in_sizes[1] / 2;     // 1000000
    const int* srcIdx = ei;
    const int* dstIdx = ei + E;

    // ---- workspace layout (floats) ----
    float* ws = (float*)d_ws;
    size_t o = 0;
    float*  h1acc  = ws + o; o += (size_t)N * 64;
    float*  nfacc  = ws + o; o += (size_t)N * 32;
    float*  edge_h = ws + o; o += 1024 * 32;
    float*  tmp    = ws + o; o += 1024 * 32;
    float*  par    = ws + o; o += (size_t)N * 128;
    __half* h1p_h  = (__half*)(ws + o); o += (size_t)N * 32;  // N*64 halfs
    __half* h2p_h  = (__half*)(ws + o); o += (size_t)N * 16;  // N*32 halfs
    __half* h2r_h  = (__half*)(ws + o); o += (size_t)N * 16;  // N*32 halfs
    int2*   epk    = (int2*)(ws + o);   o += (size_t)E * 2;
    int*    deg    = (int*)(ws + o);    o += N;
    int*    rs     = (int*)(ws + o);    o += N + 1;
    int*    cur    = (int*)(ws + o);    o += N + 1;
    int*    bsum   = (int*)(ws + o);    o += 256;
    int*    boff   = (int*)(ws + o);    o += 256;

    const int NB  = (N + 255) / 256;        // 196
    const int NBG = (N + 63) / 64;          // 782 gemm blocks
    const int NBW = (N * 64 + 255) / 256;   // wave-per-node gathers: 12500

    (void)hipMemsetAsync(deg, 0, (size_t)N * sizeof(int), stream);
    (void)hipMemsetAsync(edge_h, 0, 1024 * 32 * sizeof(float), stream);

    // 1. h1p = x @ W1 + b1  (fp16 table)
    gemm_k<64, 128, 64, 1><<<NBG, 256, 0, stream>>>(x, W1, b1, h1p_h, N, 1.f, 0);

    // 2. CSR build
    hist_k<<<(E + 255) / 256, 256, 0, stream>>>(dstIdx, deg, E);
    scan1_k<<<NB, 256, 0, stream>>>(deg, bsum, N);
    scan2_k<<<1, 256, 0, stream>>>(bsum, boff, NB, rs + N);
    scan3_k<<<NB, 256, 0, stream>>>(deg, boff, rs, cur, N);
    fill_k<<<(E + 255) / 256, 256, 0, stream>>>(srcIdx, dstIdx, ew, cur, epk, E);

    // 3. h1acc[n] = sum_{e: dst=n} w_e * h1p[src_e]   (fp16 reads, fp32 acc)
    gather64h_k<<<NBW, 256, 0, stream>>>(h1p_h, epk, rs, h1acc, N);

    // 4. h2p = relu(h1acc) @ W2 + b2  (fp16 table, 3.2MB -> L2-resident)
    gemm_k<32, 64, 64, 1><<<NBG, 256, 0, stream>>>(h1acc, W2, b2, h2p_h, N, 1.f, 1);

    // 5. h2r = relu(sum w_e * h2p[src_e])  (fp16 in, relu'd fp16 out)
    gather32h_wr_k<<<NBW, 256, 0, stream>>>(h2p_h, epk, rs, h2r_h, N);

    // 6. nfacc[n] = sum h2r[src_e]  (fp16 in, fp32 out)
    gather32h_uf_k<<<NBW, 256, 0, stream>>>(h2r_h, epk, rs, nfacc, N);

    // 7. edge_h = adj_e @ (ef @ We)
    efwe_k<<<128, 256, 0, stream>>>(ef, We, tmp);
    adjmm_k<<<512, 256, 0, stream>>>(adj, tmp, edge_h);

    // 8. par[kq] = T[:, kq*256:+256] @ edge_h[kslice]
    tgemm2_k<<<dim3(NB, 4), 256, 0, stream>>>(T, edge_h, par, N);

    // 9. out = softmax(classifier(relu(sum par + (nfacc/E)@Wn + bg)))
    classify2_k<<<NB, 256, 0, stream>>>(par, nfacc, Wn, bg, Wc1, bc1, Wc2, bc2,
                                        out, N, 1.f / (float)E);
}